// Round 7
// baseline (350.837 us; speedup 1.0000x reference)
//
#include <hip/hip_runtime.h>
#include <math.h>

typedef __attribute__((ext_vector_type(8))) short bf8;
typedef __attribute__((ext_vector_type(4))) float f4;
typedef __attribute__((ext_vector_type(2))) unsigned u2;
typedef __attribute__((ext_vector_type(4))) unsigned u4;

__device__ __forceinline__ float bf2f(short s) {
    union { unsigned u; float f; } v; v.u = ((unsigned)(unsigned short)s) << 16; return v.f;
}
// round-half-up bf16 (differs from RTNE only on exact ties)
__device__ __forceinline__ short f2bf(float f) {
    return (short)((__float_as_uint(f) + 0x8000u) >> 16);
}
// pack two fp32 -> bf16x2 (lo=a, hi=b): 2 adds + 1 v_perm
__device__ __forceinline__ unsigned pk2(float a, float b) {
    unsigned ua = __float_as_uint(a) + 0x8000u;
    unsigned ub = __float_as_uint(b) + 0x8000u;
    return __builtin_amdgcn_perm(ub, ua, 0x07060302u);
}
// async global->LDS, 16B per lane; LDS dest is wave-uniform base + lane*16
__device__ __forceinline__ void gload16(const short* g, short* l) {
    __builtin_amdgcn_global_load_lds(
        (const __attribute__((address_space(1))) void*)g,
        (__attribute__((address_space(3))) void*)l,
        16, 0, 0);
}

// ---------------------------------------------------------------------------
// x (16384,768) fp32 -> bf16 row-major, vectorized 8 elems/thread.
// ---------------------------------------------------------------------------
__global__ __launch_bounds__(256) void xb_k(const float* __restrict__ X, short* __restrict__ XB) {
    long idx = (long)blockIdx.x * 256 + threadIdx.x;   // over 16384*768/8
    const float* src = X + idx * 8;
    float4 v0 = *(const float4*)(src);
    float4 v1 = *(const float4*)(src + 4);
    u4 p; p.x = pk2(v0.x, v0.y); p.y = pk2(v0.z, v0.w);
    p.z = pk2(v1.x, v1.y); p.w = pk2(v1.z, v1.w);
    *(u4*)(XB + idx * 8) = p;
}

// ---------------------------------------------------------------------------
// Positional embedding: pos[512][768] bf16 (row 511 zero pad).
// ---------------------------------------------------------------------------
__global__ void pos_kernel(short* __restrict__ P) {
    const int row = blockIdx.x;      // 0..511
    const int j = threadIdx.x;       // 0..127  (nb = 128)
    if (row == 511) {
        for (int t = j; t < 768; t += 128) P[511 * 768 + t] = 0;
        return;
    }
    const double dist = (double)(row - 255);
    const double ad = fabs(dist);
    double hl = exp2(3.0 + 5.0 * (double)j / 127.0);
    double fe = exp(-M_LN2 / hl * ad);
    double cw = exp2((double)(j + 1)) - 1.0;
    double fc = (cw > ad) ? 1.0 : 0.0;
    double m = 2.0 + 2.0 * (double)j;
    double conc = m * m;
    double lun = (ad == 0.0) ? -INFINITY : (conc - 1.0) * log(ad);
    lun -= m * ad;
    double lnorm = lgamma(conc) - conc * log(m);
    double prob = exp(lun - lnorm) + 1e-8;
    __shared__ double red[128];
    red[j] = prob;
    __syncthreads();
    for (int s2 = 64; s2 > 0; s2 >>= 1) {
        if (j < s2) red[j] = fmax(red[j], red[j + s2]);
        __syncthreads();
    }
    double fg = prob / red[0];
    float sg = (dist > 0.0) ? 1.f : ((dist < 0.0) ? -1.f : 0.f);
    int base = row * 768;
    P[base + j]        = f2bf((float)fe);
    P[base + 128 + j]  = f2bf((float)fc);
    P[base + 256 + j]  = f2bf((float)fg);
    P[base + 384 + j]  = f2bf(sg * (float)fe);
    P[base + 512 + j]  = f2bf(sg * (float)fc);
    P[base + 640 + j]  = f2bf(sg * (float)fg);
}

// ---------------------------------------------------------------------------
// Weight transpose+convert: WT[row'][k] (bf16) = W[k][n] (fp32).
// qperm=0: row' = n.
// qperm=1 (w_qkv): n = hd*3+sel -> row' = sel*768 + hd, so each 128-wide
//                  N-block of the GEMM sees a uniform sel (Q/K/V grouped).
// ---------------------------------------------------------------------------
__global__ void wT_k(const float* __restrict__ W, short* __restrict__ WT,
                     int K, int N, int qperm) {
    int idx = blockIdx.x * 256 + threadIdx.x;          // over N * K/4
    int kq = K >> 2;
    if (idx >= N * kq) return;
    int n = idx / kq, k = (idx % kq) << 2;
    int rp = n;
    if (qperm) { int sel = n % 3, hd = n / 3; rp = sel * 768 + hd; }
    float a = W[(long)(k + 0) * N + n];
    float b = W[(long)(k + 1) * N + n];
    float c = W[(long)(k + 2) * N + n];
    float d = W[(long)(k + 3) * N + n];
    u2 r; r.x = pk2(a, b); r.y = pk2(c, d);
    *(u2*)(WT + (long)rp * K + k) = r;
}

// ---------------------------------------------------------------------------
// MFMA GEMM v3: C(MxN) = A(MxK) @ BT(NxK)^T, bf16 MFMA, fp32 accum.
// 128x128 tile, 4 waves, BK=32, DOUBLE-BUFFERED LDS (2 x 16 KB = 32 KB).
// 2-phase pipeline: issue next-tile global_load_lds BEFORE computing the
// current tile; ONE __syncthreads per K-step (its vmcnt(0) drain is the
// producer->consumer handoff; the DMA had the whole MFMA phase to land).
// LDS linear 64B rows; XOR slot swizzle slot^=((row>>1)&3) applied on BOTH
// the global source and the ds_read side -> max 2-way bank aliasing (free).
// mode 0: A bf16 row-major;             C -> bf16 (Cb)
// mode 1: A bf16 row-major;             C -> q/k/vT scatter. BT rows are
//         sel-grouped (wT_k qperm=1) so sel = n0/768 is UNIFORM per block:
//         no lane divergence, Q/K stores lane-contiguous.
//         vT layout: (b,h,window,d,j) = ((b*12+h)*32+w)*16384 + d*256 + j
// mode 2: A bf16 gather from (b,h,n,d); C -> fp32 + fp32 bias (Cf)
//         (BK=32 chunks never cross a 64-wide d-block since k0%32==0)
// ---------------------------------------------------------------------------
__global__ __launch_bounds__(256) void gemm_k(
    const short* __restrict__ A, const short* __restrict__ BT,
    int M, int N, int K, int mode,
    short* __restrict__ Cb, float* __restrict__ Cf, const float* __restrict__ bias,
    short* __restrict__ Qo, short* __restrict__ Ko, short* __restrict__ Vt)
{
    __shared__ __attribute__((aligned(16))) short lds[2][8192];  // [buf][As 4096 | Bs 4096]
    const int tid = threadIdx.x;
    const int lane = tid & 63;
    const int wave = tid >> 6;          // 0..3
    const int wm = wave >> 1, wn = wave & 1;
    const int c = lane & 15, quad = lane >> 4;
    const int m0 = blockIdx.x * 128, n0 = blockIdx.y * 128;
    const int lrow = lane >> 2;         // 0..15 (row within 16-row group)
    const int lslot = lane & 3;         // 16B slot within 64B row

    f4 acc[4][4];
#pragma unroll
    for (int i = 0; i < 4; ++i)
#pragma unroll
        for (int jx = 0; jx < 4; ++jx) acc[i][jx] = (f4){0.f, 0.f, 0.f, 0.f};

    const int nT = K >> 5;   // BK=32 steps

    // ---- staging: one K-tile (As 128x32 + Bs 128x32) into buf ----
    auto stage = [&](int buf, int k0) {
        short* As = &lds[buf][0];
        short* Bs = &lds[buf][4096];
#pragma unroll
        for (int i = 0; i < 2; ++i) {
            int grp = wave * 2 + i;              // 8 groups x 16 rows = 128 rows
            int row = grp * 16 + lrow;
            int ss = lslot ^ ((row >> 1) & 3);   // pre-swizzled source slot
            const short* srcA;
            if (mode == 2) {
                int m = m0 + row;
                srcA = A + (((long)((m >> 13) * 12 + (k0 >> 6)) * 8192 + (m & 8191)) * 64
                            + (k0 & 63) + ss * 8);
            } else {
                srcA = A + (long)(m0 + row) * K + k0 + ss * 8;
            }
            gload16(srcA, &As[grp * 512]);
            const short* srcB = BT + (long)(n0 + row) * K + k0 + ss * 8;
            gload16(srcB, &Bs[grp * 512]);
        }
    };

    stage(0, 0);
    __syncthreads();                      // prologue tile ready

    for (int t = 0, cur = 0; t < nT; ++t, cur ^= 1) {
        if (t + 1 < nT) stage(cur ^ 1, (t + 1) << 5);   // overlap DMA with MFMA
        const short* As = &lds[cur][0];
        const short* Bs = &lds[cur][4096];
        bf8 a[4], b[4];
#pragma unroll
        for (int mt = 0; mt < 4; ++mt) {
            int row = wm * 64 + mt * 16 + c;
            int slot = quad ^ ((row >> 1) & 3);
            a[mt] = *(const bf8*)(&As[row * 32 + slot * 8]);
        }
#pragma unroll
        for (int nt = 0; nt < 4; ++nt) {
            int row = wn * 64 + nt * 16 + c;
            int slot = quad ^ ((row >> 1) & 3);
            b[nt] = *(const bf8*)(&Bs[row * 32 + slot * 8]);
        }
#pragma unroll
        for (int mt = 0; mt < 4; ++mt)
#pragma unroll
            for (int nt = 0; nt < 4; ++nt)
                acc[mt][nt] = __builtin_amdgcn_mfma_f32_16x16x32_bf16(a[mt], b[nt], acc[mt][nt], 0, 0, 0);
        __syncthreads();                  // drains next-tile DMA + releases cur
    }

    if (mode == 1) {
        const int sel = n0 / 768;         // uniform per block (768/128 = 6 exact)
        if (sel == 2) {                   // V transposed: (b,h,w,d,j)
#pragma unroll
            for (int mt = 0; mt < 4; ++mt)
#pragma unroll
                for (int nt = 0; nt < 4; ++nt)
#pragma unroll
                    for (int r = 0; r < 4; ++r) {
                        int m = m0 + wm * 64 + mt * 16 + quad * 4 + r;
                        int np = n0 - 1536 + wn * 64 + nt * 16 + c;
                        int h = np >> 6, d = np & 63;
                        int bb = m >> 13, nn = m & 8191;
                        long off = ((long)((bb * 12 + h) * 32 + (nn >> 8))) * 16384 + d * 256 + (nn & 255);
                        Vt[off] = f2bf(acc[mt][nt][r]);
                    }
        } else {
            short* dst = (sel == 0) ? Qo : Ko;
            const int nb = n0 - sel * 768;
#pragma unroll
            for (int mt = 0; mt < 4; ++mt)
#pragma unroll
                for (int nt = 0; nt < 4; ++nt)
#pragma unroll
                    for (int r = 0; r < 4; ++r) {
                        int m = m0 + wm * 64 + mt * 16 + quad * 4 + r;
                        int np = nb + wn * 64 + nt * 16 + c;
                        int h = np >> 6, d = np & 63;
                        int bb = m >> 13, nn = m & 8191;
                        long off = ((long)((bb * 12 + h) * 8192 + nn)) * 64 + d;
                        dst[off] = f2bf(acc[mt][nt][r]);
                    }
        }
    } else {
#pragma unroll
        for (int mt = 0; mt < 4; ++mt)
#pragma unroll
            for (int nt = 0; nt < 4; ++nt)
#pragma unroll
                for (int r = 0; r < 4; ++r) {
                    int m = m0 + wm * 64 + mt * 16 + quad * 4 + r;
                    int n = n0 + wn * 64 + nt * 16 + c;
                    float val = acc[mt][nt][r];
                    if (mode == 2) {
                        Cf[(long)m * N + n] = val + bias[n];
                    } else {
                        Cb[(long)m * N + n] = f2bf(val);
                    }
                }
    }
}

// ---------------------------------------------------------------------------
// Fused windowed attention v5.
// Changes vs v4 (attacking the latency-bound profile: MfmaUtil 8.6, VALU 28,
// occ 21, FETCH already minimal):
// - Phase-split S (qc live, LDS-fed) from R (qp live, global-fed): register
//   sets no longer co-live -> ~114 peak VGPR -> __launch_bounds__(256,4).
// - Rotation fused into the R loop: each R tile rotated ONCE when complete
//   (rot_prev/rot_cur), 68 ds_bpermute/wave instead of 128, overlapped with
//   the R MFMAs.
// - PV processed in 8 kt-slabs with per-wave Ps[16][36] (pitch 36 -> quads
//   hit disjoint bank groups, conflict-free): LDS 50176 -> 37376 B
//   -> 4 blocks/CU (16 waves).
// ---------------------------------------------------------------------------
__global__ __launch_bounds__(256, 4) void attn_k(
    short* __restrict__ Q, const short* __restrict__ Kk, const short* __restrict__ Vt,
    const short* __restrict__ RK,   // (512,768) bf16, row 511 zero; col = h*64+d
    const float* __restrict__ rcb, const float* __restrict__ rpb)
{
    __shared__ __attribute__((aligned(16))) short Ks[256 * 64];    // then Vs[64][256]
    __shared__ __attribute__((aligned(16))) short Ps[4][16 * 36];
    const int bid = blockIdx.x;
    // window-sticky decode: bid%8 = (w&3)<<1 | (h&1); bid>>3 = strip + 4*widx
    const int low = bid & 7;
    const int wlo = low >> 1;             // w & 3
    const int hlo = low & 1;              // h & 1
    const int rest = bid >> 3;            // 0..383
    const int strip = rest & 3;
    const int t_ = rest >> 2;             // 0..95
    const int whi = t_ & 7;
    const int u_ = t_ >> 3;               // 0..11
    const int h = ((u_ % 6) << 1) | hlo;
    const int b = u_ / 6;
    const int w = (whi << 2) | wlo;
    const int tid = threadIdx.x, lane = tid & 63, wave = tid >> 6;
    const int c = lane & 15, quad = lane >> 4;
    const int i0w = strip * 64 + wave * 16;

    const long base_bh = ((long)(b * 12 + h) * 8192 + (long)w * 256) * 64;
    short* Qh = Q + base_bh;
    const short* Kh = Kk + base_bh;
    const short* Vw = Vt + (((long)(b * 12 + h) * 32 + w) << 14);   // 64x256 [d][j]
    const short* RKh = RK + h * 64;

    // ---- stage K window [j][d] -> LDS linear [256][64], swizzled source ----
#pragma unroll
    for (int i = 0; i < 8; ++i) {
        int p = tid + i * 256;
        int row = p >> 3, ls = p & 7;
        gload16(Kh + row * 64 + (ls ^ (row & 7)) * 8, &Ks[(wave * 64 + i * 256) * 8]);
    }

    // Q fragments with content / position biases added (bf16)
    bf8 qc[2], qp[2];
#pragma unroll
    for (int ks = 0; ks < 2; ++ks) {
        bf8 qraw = *(const bf8*)(Qh + (i0w + c) * 64 + ks * 32 + quad * 8);
        float4 cb0 = *(const float4*)(rcb + h * 64 + ks * 32 + quad * 8);
        float4 cb1 = *(const float4*)(rcb + h * 64 + ks * 32 + quad * 8 + 4);
        float4 pb0 = *(const float4*)(rpb + h * 64 + ks * 32 + quad * 8);
        float4 pb1 = *(const float4*)(rpb + h * 64 + ks * 32 + quad * 8 + 4);
        float cbv[8] = {cb0.x, cb0.y, cb0.z, cb0.w, cb1.x, cb1.y, cb1.z, cb1.w};
        float pbv[8] = {pb0.x, pb0.y, pb0.z, pb0.w, pb1.x, pb1.y, pb1.z, pb1.w};
#pragma unroll
        for (int u = 0; u < 8; ++u) {
            float qv = bf2f(qraw[u]);
            qc[ks][u] = f2bf(qv + cbv[u]);
            qp[ks][u] = f2bf(qv + pbv[u]);
        }
    }
    __syncthreads();   // Ks ready (drains K-stage DMA)

    // ---- Phase A: content scores S[16] from LDS (qc live) ----
    f4 S[16];
#pragma unroll
    for (int ct = 0; ct < 16; ++ct) S[ct] = (f4){0.f, 0.f, 0.f, 0.f};
#pragma unroll
    for (int t = 0; t < 16; ++t) {
        int row = t * 16 + c;
#pragma unroll
        for (int ks = 0; ks < 2; ++ks) {
            bf8 kf = *(const bf8*)(&Ks[row * 64 + (((ks * 4 + quad) ^ (row & 7))) * 8]);
            S[t] = __builtin_amdgcn_mfma_f32_16x16x32_bf16(qc[ks], kf, S[t], 0, 0, 0);
        }
    }
    __syncthreads();   // all waves done reading Ks

    // ---- re-stage same LDS with Vt window [d][j] linear [64][256], swizzled
    short* Vs = Ks;
#pragma unroll
    for (int i = 0; i < 8; ++i) {
        int p = tid + i * 256;
        int row = p >> 5, ls = p & 31;
        gload16(Vw + row * 256 + (ls ^ ((row & 7) << 2)) * 8, &Vs[(wave * 2 + i * 8) * 256]);
    }

    // ---- Phase B: position band (qp live), rotation fused per tile ----
    // pos[ip][j] = Rband[ip][15 + j - ip]; each tile rotated once on
    // completion; S[t-1] finalized from rot_prev/rot_cur.
    const int r0 = 240 - i0w;
    int src_[4];
#pragma unroll
    for (int r = 0; r < 4; ++r) {
        int ip = quad * 4 + r;
        src_[r] = (lane & 48) | ((15 - ip + c) & 15);
    }
    float rotp[4], rotc[4];
#pragma unroll
    for (int t = 0; t < 17; ++t) {
        bf8 rf0 = *(const bf8*)(RKh + (long)(r0 + t * 16 + c) * 768 + quad * 8);
        bf8 rf1 = *(const bf8*)(RKh + (long)(r0 + t * 16 + c) * 768 + 32 + quad * 8);
        f4 Rt = (f4){0.f, 0.f, 0.f, 0.f};
        Rt = __builtin_amdgcn_mfma_f32_16x16x32_bf16(qp[0], rf0, Rt, 0, 0, 0);
        Rt = __builtin_amdgcn_mfma_f32_16x16x32_bf16(qp[1], rf1, Rt, 0, 0, 0);
#pragma unroll
        for (int r = 0; r < 4; ++r) rotc[r] = __shfl(Rt[r], src_[r]);
        if (t > 0) {
#pragma unroll
            for (int r = 0; r < 4; ++r) {
                int ip = quad * 4 + r;
                float pos = (c <= ip) ? rotp[r] : rotc[r];
                S[t - 1][r] = S[t - 1][r] * 0.125f + pos;
            }
        }
#pragma unroll
        for (int r = 0; r < 4; ++r) rotp[r] = rotc[r];
    }

    // softmax over the 256 columns
    float mx[4] = {-3.4e38f, -3.4e38f, -3.4e38f, -3.4e38f};
#pragma unroll
    for (int ct = 0; ct < 16; ++ct)
#pragma unroll
        for (int r = 0; r < 4; ++r) mx[r] = fmaxf(mx[r], S[ct][r]);
#pragma unroll
    for (int r = 0; r < 4; ++r)
#pragma unroll
        for (int o = 1; o < 16; o <<= 1) mx[r] = fmaxf(mx[r], __shfl_xor(mx[r], o));
    float sm[4] = {0.f, 0.f, 0.f, 0.f};
#pragma unroll
    for (int ct = 0; ct < 16; ++ct)
#pragma unroll
        for (int r = 0; r < 4; ++r) {
            float p = __expf(S[ct][r] - mx[r]);
            S[ct][r] = p;
            sm[r] += p;
        }
#pragma unroll
    for (int r = 0; r < 4; ++r)
#pragma unroll
        for (int o = 1; o < 16; o <<= 1) sm[r] += __shfl_xor(sm[r], o);
    float inv[4];
#pragma unroll
    for (int r = 0; r < 4; ++r) inv[r] = 1.0f / sm[r];

    __syncthreads();   // Vs ready (drains V-stage DMA)

    // O = P @ V in 8 kt-slabs; Ps per-wave [16][36] (DS in-order per wave)
    f4 O[4];
#pragma unroll
    for (int vt = 0; vt < 4; ++vt) O[vt] = (f4){0.f, 0.f, 0.f, 0.f};
#pragma unroll
    for (int kt = 0; kt < 8; ++kt) {
#pragma unroll
        for (int r = 0; r < 4; ++r) {
            Ps[wave][(quad * 4 + r) * 36 + c]      = f2bf(S[kt * 2][r] * inv[r]);
            Ps[wave][(quad * 4 + r) * 36 + 16 + c] = f2bf(S[kt * 2 + 1][r] * inv[r]);
        }
        bf8 af = *(const bf8*)(&Ps[wave][c * 36 + quad * 8]);
#pragma unroll
        for (int vt = 0; vt < 4; ++vt) {
            int row = vt * 16 + c;
            int slot = ((kt * 4 + quad) ^ ((row & 7) << 2));
            bf8 bv = *(const bf8*)(&Vs[row * 256 + slot * 8]);
            O[vt] = __builtin_amdgcn_mfma_f32_16x16x32_bf16(af, bv, O[vt], 0, 0, 0);
        }
    }
    // store O in place over this wave's own q rows ((b,h,n,d) layout)
#pragma unroll
    for (int vt = 0; vt < 4; ++vt)
#pragma unroll
        for (int r = 0; r < 4; ++r)
            Qh[(i0w + quad * 4 + r) * 64 + vt * 16 + c] = f2bf(O[vt][r]);
}

// ---------------------------------------------------------------------------
extern "C" void kernel_launch(void* const* d_in, const int* in_sizes, int n_in,
                              void* d_out, int out_size, void* d_ws, size_t ws_size,
                              hipStream_t stream) {
    const float* x     = (const float*)d_in[0];   // (16384, 768)
    const float* w_qkv = (const float*)d_in[1];   // (768, 2304)
    const float* w_out = (const float*)d_in[2];   // (768, 768)
    const float* b_out = (const float*)d_in[3];   // (768,)
    const float* w_rel = (const float*)d_in[4];   // (768, 768)
    const float* rcb   = (const float*)d_in[5];   // (768,)
    const float* rpb   = (const float*)d_in[6];   // (768,)

    // ws layout (~83.0 MB), all internal buffers bf16
    char* ws = (char*)d_ws;
    short* wqkvT = (short*)(ws);                       // (2304,768)  3,538,944 B
    short* woutT = (short*)(ws + 3538944L);            // (768,768)   1,179,648 B
    short* wrelT = (short*)(ws + 4718592L);            // (768,768)   1,179,648 B
    short* pos   = (short*)(ws + 5898240L);            // (512,768)     786,432 B
    short* relk  = (short*)(ws + 6684672L);            // (512,768)     786,432 B
    short* q     = (short*)(ws + 7471104L);            // 25,165,824 B
    short* k     = (short*)(ws + 32636928L);
    short* vT    = (short*)(ws + 57802752L);
    // xb (16384,768) bf16 lives in d_out: dead until the final GEMM overwrites it
    short* xb    = (short*)d_out;                      // 25,165,824 B < out_size

    // weight transpose+convert (fp32 -> bf16 [n][k]); w_qkv rows sel-grouped
    wT_k<<<(2304 * 192 + 255) / 256, 256, 0, stream>>>(w_qkv, wqkvT, 768, 2304, 1);
    wT_k<<<(768 * 192 + 255) / 256, 256, 0, stream>>>(w_out, woutT, 768, 768, 0);
    wT_k<<<(768 * 192 + 255) / 256, 256, 0, stream>>>(w_rel, wrelT, 768, 768, 0);
    pos_kernel<<<512, 128, 0, stream>>>(pos);
    xb_k<<<6144, 256, 0, stream>>>(x, xb);
    // rel_k = positions @ w_rel   (512 x 768)
    gemm_k<<<dim3(4, 6), 256, 0, stream>>>(pos, wrelT, 512, 768, 768, 0,
                                           relk, nullptr, nullptr, nullptr, nullptr, nullptr);
    // qkv = xb @ w_qkv (sel-grouped), de-interleaved into q/k (b,h,n,d), vT (b,h,w,d,j)
    gemm_k<<<dim3(128, 18), 256, 0, stream>>>(xb, wqkvT, 16384, 2304, 768, 1,
                                              nullptr, nullptr, nullptr, q, k, vT);
    // fused windowed attention; output overwrites q in place
    attn_k<<<3072, 256, 0, stream>>>(q, k, vT, relk, rcb, rpb);
    // out = attn_out @ w_out + b_out
    gemm_k<<<dim3(128, 6), 256, 0, stream>>>(q, woutT, 16384, 768, 768, 2,
                                             nullptr, (float*)d_out, b_out, nullptr, nullptr, nullptr);
}

// Round 8
// 332.336 us; speedup vs baseline: 1.0557x; 1.0557x over previous
//
#include <hip/hip_runtime.h>
#include <math.h>

typedef __attribute__((ext_vector_type(8))) short bf8;
typedef __attribute__((ext_vector_type(4))) float f4;
typedef __attribute__((ext_vector_type(2))) unsigned u2;
typedef __attribute__((ext_vector_type(4))) unsigned u4;

__device__ __forceinline__ float bf2f(short s) {
    union { unsigned u; float f; } v; v.u = ((unsigned)(unsigned short)s) << 16; return v.f;
}
// round-half-up bf16 (differs from RTNE only on exact ties)
__device__ __forceinline__ short f2bf(float f) {
    return (short)((__float_as_uint(f) + 0x8000u) >> 16);
}
// pack two fp32 -> bf16x2 (lo=a, hi=b): 2 adds + 1 v_perm
__device__ __forceinline__ unsigned pk2(float a, float b) {
    unsigned ua = __float_as_uint(a) + 0x8000u;
    unsigned ub = __float_as_uint(b) + 0x8000u;
    return __builtin_amdgcn_perm(ub, ua, 0x07060302u);
}
// async global->LDS, 16B per lane; LDS dest is wave-uniform base + lane*16
__device__ __forceinline__ void gload16(const short* g, short* l) {
    __builtin_amdgcn_global_load_lds(
        (const __attribute__((address_space(1))) void*)g,
        (__attribute__((address_space(3))) void*)l,
        16, 0, 0);
}

// ---------------------------------------------------------------------------
// x (16384,768) fp32 -> bf16 row-major, vectorized 8 elems/thread.
// ---------------------------------------------------------------------------
__global__ __launch_bounds__(256) void xb_k(const float* __restrict__ X, short* __restrict__ XB) {
    long idx = (long)blockIdx.x * 256 + threadIdx.x;   // over 16384*768/8
    const float* src = X + idx * 8;
    float4 v0 = *(const float4*)(src);
    float4 v1 = *(const float4*)(src + 4);
    u4 p; p.x = pk2(v0.x, v0.y); p.y = pk2(v0.z, v0.w);
    p.z = pk2(v1.x, v1.y); p.w = pk2(v1.z, v1.w);
    *(u4*)(XB + idx * 8) = p;
}

// ---------------------------------------------------------------------------
// Positional embedding: pos[512][768] bf16 (row 511 zero pad).
// ---------------------------------------------------------------------------
__global__ void pos_kernel(short* __restrict__ P) {
    const int row = blockIdx.x;      // 0..511
    const int j = threadIdx.x;       // 0..127  (nb = 128)
    if (row == 511) {
        for (int t = j; t < 768; t += 128) P[511 * 768 + t] = 0;
        return;
    }
    const double dist = (double)(row - 255);
    const double ad = fabs(dist);
    double hl = exp2(3.0 + 5.0 * (double)j / 127.0);
    double fe = exp(-M_LN2 / hl * ad);
    double cw = exp2((double)(j + 1)) - 1.0;
    double fc = (cw > ad) ? 1.0 : 0.0;
    double m = 2.0 + 2.0 * (double)j;
    double conc = m * m;
    double lun = (ad == 0.0) ? -INFINITY : (conc - 1.0) * log(ad);
    lun -= m * ad;
    double lnorm = lgamma(conc) - conc * log(m);
    double prob = exp(lun - lnorm) + 1e-8;
    __shared__ double red[128];
    red[j] = prob;
    __syncthreads();
    for (int s2 = 64; s2 > 0; s2 >>= 1) {
        if (j < s2) red[j] = fmax(red[j], red[j + s2]);
        __syncthreads();
    }
    double fg = prob / red[0];
    float sg = (dist > 0.0) ? 1.f : ((dist < 0.0) ? -1.f : 0.f);
    int base = row * 768;
    P[base + j]        = f2bf((float)fe);
    P[base + 128 + j]  = f2bf((float)fc);
    P[base + 256 + j]  = f2bf((float)fg);
    P[base + 384 + j]  = f2bf(sg * (float)fe);
    P[base + 512 + j]  = f2bf(sg * (float)fc);
    P[base + 640 + j]  = f2bf(sg * (float)fg);
}

// ---------------------------------------------------------------------------
// Weight transpose+convert: WT[row'][k] (bf16) = W[k][n] (fp32).
// qperm=0: row' = n.
// qperm=1 (w_qkv): n = hd*3+sel -> row' = sel*768 + hd, so each 128-wide
//                  N-block of the GEMM sees a uniform sel (Q/K/V grouped).
// ---------------------------------------------------------------------------
__global__ void wT_k(const float* __restrict__ W, short* __restrict__ WT,
                     int K, int N, int qperm) {
    int idx = blockIdx.x * 256 + threadIdx.x;          // over N * K/4
    int kq = K >> 2;
    if (idx >= N * kq) return;
    int n = idx / kq, k = (idx % kq) << 2;
    int rp = n;
    if (qperm) { int sel = n % 3, hd = n / 3; rp = sel * 768 + hd; }
    float a = W[(long)(k + 0) * N + n];
    float b = W[(long)(k + 1) * N + n];
    float c = W[(long)(k + 2) * N + n];
    float d = W[(long)(k + 3) * N + n];
    u2 r; r.x = pk2(a, b); r.y = pk2(c, d);
    *(u2*)(WT + (long)rp * K + k) = r;
}

// ---------------------------------------------------------------------------
// MFMA GEMM v3: C(MxN) = A(MxK) @ BT(NxK)^T, bf16 MFMA, fp32 accum.
// 128x128 tile, 4 waves, BK=32, DOUBLE-BUFFERED LDS (2 x 16 KB = 32 KB).
// 2-phase pipeline: issue next-tile global_load_lds BEFORE computing the
// current tile; ONE __syncthreads per K-step (its vmcnt(0) drain is the
// producer->consumer handoff; the DMA had the whole MFMA phase to land).
// LDS linear 64B rows; XOR slot swizzle slot^=((row>>1)&3) applied on BOTH
// the global source and the ds_read side -> max 2-way bank aliasing (free).
// mode 0: A bf16 row-major;             C -> bf16 (Cb)
// mode 1: A bf16 row-major;             C -> q/k/vT scatter. BT rows are
//         sel-grouped (wT_k qperm=1) so sel = n0/768 is UNIFORM per block:
//         no lane divergence, Q/K stores lane-contiguous.
//         vT layout: (b,h,window,d,j) = ((b*12+h)*32+w)*16384 + d*256 + j
// mode 2: A bf16 gather from (b,h,n,d); C -> fp32 + fp32 bias (Cf)
//         (BK=32 chunks never cross a 64-wide d-block since k0%32==0)
// ---------------------------------------------------------------------------
__global__ __launch_bounds__(256) void gemm_k(
    const short* __restrict__ A, const short* __restrict__ BT,
    int M, int N, int K, int mode,
    short* __restrict__ Cb, float* __restrict__ Cf, const float* __restrict__ bias,
    short* __restrict__ Qo, short* __restrict__ Ko, short* __restrict__ Vt)
{
    __shared__ __attribute__((aligned(16))) short lds[2][8192];  // [buf][As 4096 | Bs 4096]
    const int tid = threadIdx.x;
    const int lane = tid & 63;
    const int wave = tid >> 6;          // 0..3
    const int wm = wave >> 1, wn = wave & 1;
    const int c = lane & 15, quad = lane >> 4;
    const int m0 = blockIdx.x * 128, n0 = blockIdx.y * 128;
    const int lrow = lane >> 2;         // 0..15 (row within 16-row group)
    const int lslot = lane & 3;         // 16B slot within 64B row

    f4 acc[4][4];
#pragma unroll
    for (int i = 0; i < 4; ++i)
#pragma unroll
        for (int jx = 0; jx < 4; ++jx) acc[i][jx] = (f4){0.f, 0.f, 0.f, 0.f};

    const int nT = K >> 5;   // BK=32 steps

    // ---- staging: one K-tile (As 128x32 + Bs 128x32) into buf ----
    auto stage = [&](int buf, int k0) {
        short* As = &lds[buf][0];
        short* Bs = &lds[buf][4096];
#pragma unroll
        for (int i = 0; i < 2; ++i) {
            int grp = wave * 2 + i;              // 8 groups x 16 rows = 128 rows
            int row = grp * 16 + lrow;
            int ss = lslot ^ ((row >> 1) & 3);   // pre-swizzled source slot
            const short* srcA;
            if (mode == 2) {
                int m = m0 + row;
                srcA = A + (((long)((m >> 13) * 12 + (k0 >> 6)) * 8192 + (m & 8191)) * 64
                            + (k0 & 63) + ss * 8);
            } else {
                srcA = A + (long)(m0 + row) * K + k0 + ss * 8;
            }
            gload16(srcA, &As[grp * 512]);
            const short* srcB = BT + (long)(n0 + row) * K + k0 + ss * 8;
            gload16(srcB, &Bs[grp * 512]);
        }
    };

    stage(0, 0);
    __syncthreads();                      // prologue tile ready

    for (int t = 0, cur = 0; t < nT; ++t, cur ^= 1) {
        if (t + 1 < nT) stage(cur ^ 1, (t + 1) << 5);   // overlap DMA with MFMA
        const short* As = &lds[cur][0];
        const short* Bs = &lds[cur][4096];
        bf8 a[4], b[4];
#pragma unroll
        for (int mt = 0; mt < 4; ++mt) {
            int row = wm * 64 + mt * 16 + c;
            int slot = quad ^ ((row >> 1) & 3);
            a[mt] = *(const bf8*)(&As[row * 32 + slot * 8]);
        }
#pragma unroll
        for (int nt = 0; nt < 4; ++nt) {
            int row = wn * 64 + nt * 16 + c;
            int slot = quad ^ ((row >> 1) & 3);
            b[nt] = *(const bf8*)(&Bs[row * 32 + slot * 8]);
        }
#pragma unroll
        for (int mt = 0; mt < 4; ++mt)
#pragma unroll
            for (int nt = 0; nt < 4; ++nt)
                acc[mt][nt] = __builtin_amdgcn_mfma_f32_16x16x32_bf16(a[mt], b[nt], acc[mt][nt], 0, 0, 0);
        __syncthreads();                  // drains next-tile DMA + releases cur
    }

    if (mode == 1) {
        const int sel = n0 / 768;         // uniform per block (768/128 = 6 exact)
        if (sel == 2) {                   // V transposed: (b,h,w,d,j)
#pragma unroll
            for (int mt = 0; mt < 4; ++mt)
#pragma unroll
                for (int nt = 0; nt < 4; ++nt)
#pragma unroll
                    for (int r = 0; r < 4; ++r) {
                        int m = m0 + wm * 64 + mt * 16 + quad * 4 + r;
                        int np = n0 - 1536 + wn * 64 + nt * 16 + c;
                        int h = np >> 6, d = np & 63;
                        int bb = m >> 13, nn = m & 8191;
                        long off = ((long)((bb * 12 + h) * 32 + (nn >> 8))) * 16384 + d * 256 + (nn & 255);
                        Vt[off] = f2bf(acc[mt][nt][r]);
                    }
        } else {
            short* dst = (sel == 0) ? Qo : Ko;
            const int nb = n0 - sel * 768;
#pragma unroll
            for (int mt = 0; mt < 4; ++mt)
#pragma unroll
                for (int nt = 0; nt < 4; ++nt)
#pragma unroll
                    for (int r = 0; r < 4; ++r) {
                        int m = m0 + wm * 64 + mt * 16 + quad * 4 + r;
                        int np = nb + wn * 64 + nt * 16 + c;
                        int h = np >> 6, d = np & 63;
                        int bb = m >> 13, nn = m & 8191;
                        long off = ((long)((bb * 12 + h) * 8192 + nn)) * 64 + d;
                        dst[off] = f2bf(acc[mt][nt][r]);
                    }
        }
    } else {
#pragma unroll
        for (int mt = 0; mt < 4; ++mt)
#pragma unroll
            for (int nt = 0; nt < 4; ++nt)
#pragma unroll
                for (int r = 0; r < 4; ++r) {
                    int m = m0 + wm * 64 + mt * 16 + quad * 4 + r;
                    int n = n0 + wn * 64 + nt * 16 + c;
                    float val = acc[mt][nt][r];
                    if (mode == 2) {
                        Cf[(long)m * N + n] = val + bias[n];
                    } else {
                        Cb[(long)m * N + n] = f2bf(val);
                    }
                }
    }
}

// ---------------------------------------------------------------------------
// Fused windowed attention v6 (= v5 minus the spill-inducing occupancy bound).
// v5's __launch_bounds__(256,4) capped the allocator below the ~110-reg live
// set (S[16] alone = 64 VGPRs) -> scratch spill: WRITE_SIZE 24.5->135 MB,
// FETCH 40->95 MB, +9 us despite 2x occupancy. Plain (256) lets the allocator
// land ~110-125 VGPR: <=128 still allows 4 waves/SIMD, and LDS 37376 allows
// 4 blocks/CU, so the occupancy gain survives WITHOUT spill.
// Structure (kept from v5):
// - Phase-split S (qc live, LDS-fed) from R (qp live, global-fed).
// - Rotation fused into the R loop (68 ds_bpermute/wave, overlapped w/ MFMA).
// - PV in 8 kt-slabs, per-wave Ps[16][36]: LDS 37376 B.
// ---------------------------------------------------------------------------
__global__ __launch_bounds__(256) void attn_k(
    short* __restrict__ Q, const short* __restrict__ Kk, const short* __restrict__ Vt,
    const short* __restrict__ RK,   // (512,768) bf16, row 511 zero; col = h*64+d
    const float* __restrict__ rcb, const float* __restrict__ rpb)
{
    __shared__ __attribute__((aligned(16))) short Ks[256 * 64];    // then Vs[64][256]
    __shared__ __attribute__((aligned(16))) short Ps[4][16 * 36];
    const int bid = blockIdx.x;
    // window-sticky decode: bid%8 = (w&3)<<1 | (h&1); bid>>3 = strip + 4*widx
    const int low = bid & 7;
    const int wlo = low >> 1;             // w & 3
    const int hlo = low & 1;              // h & 1
    const int rest = bid >> 3;            // 0..383
    const int strip = rest & 3;
    const int t_ = rest >> 2;             // 0..95
    const int whi = t_ & 7;
    const int u_ = t_ >> 3;               // 0..11
    const int h = ((u_ % 6) << 1) | hlo;
    const int b = u_ / 6;
    const int w = (whi << 2) | wlo;
    const int tid = threadIdx.x, lane = tid & 63, wave = tid >> 6;
    const int c = lane & 15, quad = lane >> 4;
    const int i0w = strip * 64 + wave * 16;

    const long base_bh = ((long)(b * 12 + h) * 8192 + (long)w * 256) * 64;
    short* Qh = Q + base_bh;
    const short* Kh = Kk + base_bh;
    const short* Vw = Vt + (((long)(b * 12 + h) * 32 + w) << 14);   // 64x256 [d][j]
    const short* RKh = RK + h * 64;

    // ---- stage K window [j][d] -> LDS linear [256][64], swizzled source ----
#pragma unroll
    for (int i = 0; i < 8; ++i) {
        int p = tid + i * 256;
        int row = p >> 3, ls = p & 7;
        gload16(Kh + row * 64 + (ls ^ (row & 7)) * 8, &Ks[(wave * 64 + i * 256) * 8]);
    }

    // Q fragments with content / position biases added (bf16)
    bf8 qc[2], qp[2];
#pragma unroll
    for (int ks = 0; ks < 2; ++ks) {
        bf8 qraw = *(const bf8*)(Qh + (i0w + c) * 64 + ks * 32 + quad * 8);
        float4 cb0 = *(const float4*)(rcb + h * 64 + ks * 32 + quad * 8);
        float4 cb1 = *(const float4*)(rcb + h * 64 + ks * 32 + quad * 8 + 4);
        float4 pb0 = *(const float4*)(rpb + h * 64 + ks * 32 + quad * 8);
        float4 pb1 = *(const float4*)(rpb + h * 64 + ks * 32 + quad * 8 + 4);
        float cbv[8] = {cb0.x, cb0.y, cb0.z, cb0.w, cb1.x, cb1.y, cb1.z, cb1.w};
        float pbv[8] = {pb0.x, pb0.y, pb0.z, pb0.w, pb1.x, pb1.y, pb1.z, pb1.w};
#pragma unroll
        for (int u = 0; u < 8; ++u) {
            float qv = bf2f(qraw[u]);
            qc[ks][u] = f2bf(qv + cbv[u]);
            qp[ks][u] = f2bf(qv + pbv[u]);
        }
    }
    __syncthreads();   // Ks ready (drains K-stage DMA)

    // ---- Phase A: content scores S[16] from LDS (qc live) ----
    f4 S[16];
#pragma unroll
    for (int ct = 0; ct < 16; ++ct) S[ct] = (f4){0.f, 0.f, 0.f, 0.f};
#pragma unroll
    for (int t = 0; t < 16; ++t) {
        int row = t * 16 + c;
#pragma unroll
        for (int ks = 0; ks < 2; ++ks) {
            bf8 kf = *(const bf8*)(&Ks[row * 64 + (((ks * 4 + quad) ^ (row & 7))) * 8]);
            S[t] = __builtin_amdgcn_mfma_f32_16x16x32_bf16(qc[ks], kf, S[t], 0, 0, 0);
        }
    }
    __syncthreads();   // all waves done reading Ks

    // ---- re-stage same LDS with Vt window [d][j] linear [64][256], swizzled
    short* Vs = Ks;
#pragma unroll
    for (int i = 0; i < 8; ++i) {
        int p = tid + i * 256;
        int row = p >> 5, ls = p & 31;
        gload16(Vw + row * 256 + (ls ^ ((row & 7) << 2)) * 8, &Vs[(wave * 2 + i * 8) * 256]);
    }

    // ---- Phase B: position band (qp live), rotation fused per tile ----
    // pos[ip][j] = Rband[ip][15 + j - ip]; each tile rotated once on
    // completion; S[t-1] finalized from rot_prev/rot_cur.
    const int r0 = 240 - i0w;
    int src_[4];
#pragma unroll
    for (int r = 0; r < 4; ++r) {
        int ip = quad * 4 + r;
        src_[r] = (lane & 48) | ((15 - ip + c) & 15);
    }
    float rotp[4], rotc[4];
#pragma unroll
    for (int t = 0; t < 17; ++t) {
        bf8 rf0 = *(const bf8*)(RKh + (long)(r0 + t * 16 + c) * 768 + quad * 8);
        bf8 rf1 = *(const bf8*)(RKh + (long)(r0 + t * 16 + c) * 768 + 32 + quad * 8);
        f4 Rt = (f4){0.f, 0.f, 0.f, 0.f};
        Rt = __builtin_amdgcn_mfma_f32_16x16x32_bf16(qp[0], rf0, Rt, 0, 0, 0);
        Rt = __builtin_amdgcn_mfma_f32_16x16x32_bf16(qp[1], rf1, Rt, 0, 0, 0);
#pragma unroll
        for (int r = 0; r < 4; ++r) rotc[r] = __shfl(Rt[r], src_[r]);
        if (t > 0) {
#pragma unroll
            for (int r = 0; r < 4; ++r) {
                int ip = quad * 4 + r;
                float pos = (c <= ip) ? rotp[r] : rotc[r];
                S[t - 1][r] = S[t - 1][r] * 0.125f + pos;
            }
        }
#pragma unroll
        for (int r = 0; r < 4; ++r) rotp[r] = rotc[r];
    }

    // softmax over the 256 columns
    float mx[4] = {-3.4e38f, -3.4e38f, -3.4e38f, -3.4e38f};
#pragma unroll
    for (int ct = 0; ct < 16; ++ct)
#pragma unroll
        for (int r = 0; r < 4; ++r) mx[r] = fmaxf(mx[r], S[ct][r]);
#pragma unroll
    for (int r = 0; r < 4; ++r)
#pragma unroll
        for (int o = 1; o < 16; o <<= 1) mx[r] = fmaxf(mx[r], __shfl_xor(mx[r], o));
    float sm[4] = {0.f, 0.f, 0.f, 0.f};
#pragma unroll
    for (int ct = 0; ct < 16; ++ct)
#pragma unroll
        for (int r = 0; r < 4; ++r) {
            float p = __expf(S[ct][r] - mx[r]);
            S[ct][r] = p;
            sm[r] += p;
        }
#pragma unroll
    for (int r = 0; r < 4; ++r)
#pragma unroll
        for (int o = 1; o < 16; o <<= 1) sm[r] += __shfl_xor(sm[r], o);
    float inv[4];
#pragma unroll
    for (int r = 0; r < 4; ++r) inv[r] = 1.0f / sm[r];

    __syncthreads();   // Vs ready (drains V-stage DMA)

    // O = P @ V in 8 kt-slabs; Ps per-wave [16][36] (DS in-order per wave)
    f4 O[4];
#pragma unroll
    for (int vt = 0; vt < 4; ++vt) O[vt] = (f4){0.f, 0.f, 0.f, 0.f};
#pragma unroll
    for (int kt = 0; kt < 8; ++kt) {
#pragma unroll
        for (int r = 0; r < 4; ++r) {
            Ps[wave][(quad * 4 + r) * 36 + c]      = f2bf(S[kt * 2][r] * inv[r]);
            Ps[wave][(quad * 4 + r) * 36 + 16 + c] = f2bf(S[kt * 2 + 1][r] * inv[r]);
        }
        bf8 af = *(const bf8*)(&Ps[wave][c * 36 + quad * 8]);
#pragma unroll
        for (int vt = 0; vt < 4; ++vt) {
            int row = vt * 16 + c;
            int slot = ((kt * 4 + quad) ^ ((row & 7) << 2));
            bf8 bv = *(const bf8*)(&Vs[row * 256 + slot * 8]);
            O[vt] = __builtin_amdgcn_mfma_f32_16x16x32_bf16(af, bv, O[vt], 0, 0, 0);
        }
    }
    // store O in place over this wave's own q rows ((b,h,n,d) layout)
#pragma unroll
    for (int vt = 0; vt < 4; ++vt)
#pragma unroll
        for (int r = 0; r < 4; ++r)
            Qh[(i0w + quad * 4 + r) * 64 + vt * 16 + c] = f2bf(O[vt][r]);
}

// ---------------------------------------------------------------------------
extern "C" void kernel_launch(void* const* d_in, const int* in_sizes, int n_in,
                              void* d_out, int out_size, void* d_ws, size_t ws_size,
                              hipStream_t stream) {
    const float* x     = (const float*)d_in[0];   // (16384, 768)
    const float* w_qkv = (const float*)d_in[1];   // (768, 2304)
    const float* w_out = (const float*)d_in[2];   // (768, 768)
    const float* b_out = (const float*)d_in[3];   // (768,)
    const float* w_rel = (const float*)d_in[4];   // (768, 768)
    const float* rcb   = (const float*)d_in[5];   // (768,)
    const float* rpb   = (const float*)d_in[6];   // (768,)

    // ws layout (~83.0 MB), all internal buffers bf16
    char* ws = (char*)d_ws;
    short* wqkvT = (short*)(ws);                       // (2304,768)  3,538,944 B
    short* woutT = (short*)(ws + 3538944L);            // (768,768)   1,179,648 B
    short* wrelT = (short*)(ws + 4718592L);            // (768,768)   1,179,648 B
    short* pos   = (short*)(ws + 5898240L);            // (512,768)     786,432 B
    short* relk  = (short*)(ws + 6684672L);            // (512,768)     786,432 B
    short* q     = (short*)(ws + 7471104L);            // 25,165,824 B
    short* k     = (short*)(ws + 32636928L);
    short* vT    = (short*)(ws + 57802752L);
    // xb (16384,768) bf16 lives in d_out: dead until the final GEMM overwrites it
    short* xb    = (short*)d_out;                      // 25,165,824 B < out_size

    // weight transpose+convert (fp32 -> bf16 [n][k]); w_qkv rows sel-grouped
    wT_k<<<(2304 * 192 + 255) / 256, 256, 0, stream>>>(w_qkv, wqkvT, 768, 2304, 1);
    wT_k<<<(768 * 192 + 255) / 256, 256, 0, stream>>>(w_out, woutT, 768, 768, 0);
    wT_k<<<(768 * 192 + 255) / 256, 256, 0, stream>>>(w_rel, wrelT, 768, 768, 0);
    pos_kernel<<<512, 128, 0, stream>>>(pos);
    xb_k<<<6144, 256, 0, stream>>>(x, xb);
    // rel_k = positions @ w_rel   (512 x 768)
    gemm_k<<<dim3(4, 6), 256, 0, stream>>>(pos, wrelT, 512, 768, 768, 0,
                                           relk, nullptr, nullptr, nullptr, nullptr, nullptr);
    // qkv = xb @ w_qkv (sel-grouped), de-interleaved into q/k (b,h,n,d), vT (b,h,w,d,j)
    gemm_k<<<dim3(128, 18), 256, 0, stream>>>(xb, wqkvT, 16384, 2304, 768, 1,
                                              nullptr, nullptr, nullptr, q, k, vT);
    // fused windowed attention; output overwrites q in place
    attn_k<<<3072, 256, 0, stream>>>(q, k, vT, relk, rcb, rpb);
    // out = attn_out @ w_out + b_out
    gemm_k<<<dim3(128, 6), 256, 0, stream>>>(q, woutT, 16384, 768, 768, 2,
                                             nullptr, (float*)d_out, b_out, nullptr, nullptr, nullptr);
}